// Round 19
// baseline (78.680 us; speedup 1.0000x reference)
//
#include <hip/hip_runtime.h>
#include <hip/hip_bf16.h>

// Pipeline (chain = b*768 + c1, 12288 chains):
//  d_ws  : xt [12288][1024] bf16 (interior 32x32 conv outputs ONLY) = 25.2 MB.
//          Borders of the 34x34 grid are synthesized as bias[c1] in the scan.
//  d_out : scratch for A_bf (im2col x, [16384][768] bf16, 25.2 MB) + W_bf
//          ([768][768] bf16, 1.18 MB); fully overwritten by scan_emit_k.
//  1) prep_k        : x -> A_bf (im2col), w -> W_bf  (one launch)
//  2) conv_gemm_k   : R7-verbatim global_load_lds GEMM — zero staging VALU,
//                     width-16 async loads with inverse-swizzled SOURCE
//                     ((row>>1)&3 chunk XOR -> 0 bank conflicts), 128x128
//                     tile, 4 waves, BK=32 dbuf, packed us4 bf16 epilogue.
//  3) scan_emit_k   : R18-verbatim wave-parallel recurrence (8 DS-ops/row,
//                     rolled heads + Rr=prev D3), 4-row prefetch, 3-step
//                     Hillis-Steele, border synthesis, incremental crop emit.

typedef __attribute__((ext_vector_type(8))) short s8v;     // 8 bf16
typedef __attribute__((ext_vector_type(4))) float f4v;     // MFMA acc
typedef __attribute__((ext_vector_type(8))) unsigned short us8;
typedef __attribute__((ext_vector_type(4))) unsigned short us4;

__device__ __forceinline__ unsigned short f2bf(float f) {
    __hip_bfloat16 h = __float2bfloat16(f);
    return *reinterpret_cast<unsigned short*>(&h);
}
__device__ __forceinline__ float bf2f(unsigned short u) {
    union { unsigned int i; float f; } c; c.i = (unsigned int)u << 16; return c.f;
}

__device__ __forceinline__ void gload_lds16(const void* g, void* l) {
    __builtin_amdgcn_global_load_lds(
        (const __attribute__((address_space(1))) unsigned int*)g,
        (__attribute__((address_space(3))) unsigned int*)l,
        16, 0, 0);
}

// block ranges: [0,6144) convert_x, [6144,6432) convert_w
__global__ __launch_bounds__(256) void prep_k(const float* __restrict__ x,
                                              const float* __restrict__ w,
                                              unsigned short* __restrict__ a_bf,
                                              unsigned short* __restrict__ w_bf) {
    const int bid = blockIdx.x;
    if (bid < 6144) {
        // x [16][3][512][512] f32 -> A_bf [16384][768], m=(b,ph,pw), k=(c,py,px)
        int g = bid * 256 + threadIdx.x;
        int f = g << 3;
        int wc = f & 511;
        int h  = (f >> 9) & 511;
        int cb = f >> 18;
        int c  = cb % 3, b = cb / 3;
        const float4 v0 = *(const float4*)(x + f);
        const float4 v1 = *(const float4*)(x + f + 4);
        int m = (b << 10) + ((h >> 4) << 5) + (wc >> 4);
        int k = (c << 8) + ((h & 15) << 4) + (wc & 15);
        us8 o;
        o[0] = f2bf(v0.x); o[1] = f2bf(v0.y); o[2] = f2bf(v0.z); o[3] = f2bf(v0.w);
        o[4] = f2bf(v1.x); o[5] = f2bf(v1.y); o[6] = f2bf(v1.z); o[7] = f2bf(v1.w);
        *(us8*)(a_bf + (size_t)m * 768 + k) = o;
    } else {
        int g = (bid - 6144) * 256 + threadIdx.x;
        int f = g << 3;
        const float4 v0 = *(const float4*)(w + f);
        const float4 v1 = *(const float4*)(w + f + 4);
        us8 u;
        u[0] = f2bf(v0.x); u[1] = f2bf(v0.y); u[2] = f2bf(v0.z); u[3] = f2bf(v0.w);
        u[4] = f2bf(v1.x); u[5] = f2bf(v1.y); u[6] = f2bf(v1.z); u[7] = f2bf(v1.w);
        *(us8*)(w_bf + f) = u;
    }
}

// C[m][n] = sum_k A[m][k]*W[n][k]; 128x128 tile, BK=32, 4 waves, 2-phase dbuf.
// LDS(row, chunk) holds global chunk (chunk ^ ((row>>1)&3)): inverse-swizzle
// on the global SOURCE address (stage), same XOR on the ds_read (read).
__global__ __launch_bounds__(256) void conv_gemm_k(const unsigned short* __restrict__ A,
                                                   const unsigned short* __restrict__ W,
                                                   const float* __restrict__ bias,
                                                   unsigned short* __restrict__ xt) {
    __shared__ __align__(16) unsigned short As[2][128 * 32];
    __shared__ __align__(16) unsigned short Bs[2][128 * 32];
    const int tid  = threadIdx.x;
    const int lane = tid & 63, wv = tid >> 6;
    const int wr = wv >> 1, wc = wv & 1;
    const int m0 = blockIdx.x << 7, n0 = blockIdx.y << 7;
    const int bb = m0 >> 10;

    f4v acc[4][4] = {};

    const int l2 = lane >> 2;
    const int kx = ((lane & 3) ^ ((l2 >> 1) & 3)) << 3;   // inverse-swizzled source
    const unsigned short* gA = A + (size_t)(m0 + (wv << 5) + l2) * 768 + kx;
    const unsigned short* gB = W + (size_t)(n0 + (wv << 5) + l2) * 768 + kx;

    auto stage = [&](int buf, int k0) {
        gload_lds16(gA + k0,            As[buf] + (wv << 10));
        gload_lds16(gA + k0 + 16 * 768, As[buf] + (wv << 10) + 512);
        gload_lds16(gB + k0,            Bs[buf] + (wv << 10));
        gload_lds16(gB + k0 + 16 * 768, Bs[buf] + (wv << 10) + 512);
    };

    stage(0, 0);
    asm volatile("s_waitcnt vmcnt(0)" ::: "memory");
    __syncthreads();

    const int cq = lane >> 4, l15 = lane & 15;
    int cur = 0;
    for (int t = 0; t < 24; ++t) {
        if (t < 23) stage(cur ^ 1, (t + 1) << 5);      // prefetch next K-tile
        s8v a[4], b[4];
        #pragma unroll
        for (int mi = 0; mi < 4; ++mi) {
            int ra = (wr << 6) + (mi << 4) + l15;
            a[mi] = *(const s8v*)(As[cur] + (ra << 5) + ((cq ^ ((ra >> 1) & 3)) << 3));
        }
        #pragma unroll
        for (int ni = 0; ni < 4; ++ni) {
            int rb = (wc << 6) + (ni << 4) + l15;
            b[ni] = *(const s8v*)(Bs[cur] + (rb << 5) + ((cq ^ ((rb >> 1) & 3)) << 3));
        }
        #pragma unroll
        for (int mi = 0; mi < 4; ++mi)
            #pragma unroll
            for (int ni = 0; ni < 4; ++ni)
                acc[mi][ni] = __builtin_amdgcn_mfma_f32_16x16x32_bf16(a[mi], b[ni], acc[mi][ni], 0, 0, 0);
        asm volatile("s_waitcnt vmcnt(0)" ::: "memory");
        __syncthreads();
        cur ^= 1;
    }

    // packed bf16 epilogue: lane owns 4 consecutive pw (acc regs) at one n
    #pragma unroll
    for (int mi = 0; mi < 4; ++mi) {
        int m  = m0 + (wr << 6) + (mi << 4) + (cq << 2);
        int ph = (m >> 5) & 31, pwm = m & 31;
        unsigned short* dst = xt + (((size_t)bb * 768) << 10) + (ph << 5) + pwm;
        #pragma unroll
        for (int ni = 0; ni < 4; ++ni) {
            int n = n0 + (wc << 6) + (ni << 4) + l15;
            float bv = bias[n];
            us4 o;
            o[0] = f2bf(acc[mi][ni][0] + bv);
            o[1] = f2bf(acc[mi][ni][1] + bv);
            o[2] = f2bf(acc[mi][ni][2] + bv);
            o[3] = f2bf(acc[mi][ni][3] + bv);
            *(us4*)(dst + ((size_t)n << 10)) = o;
        }
    }
}

// Wave-parallel scan + fused crop: ONE chain per 32-lane group (12288 groups).
// Shuffle-rolled: 8 DS ops per row (heads roll; Rr = previous iter's D3).
__global__ __launch_bounds__(256) void scan_emit_k(const unsigned short* __restrict__ xt,
                                                   const float* __restrict__ bias,
                                                   float* __restrict__ out) {
    const int grp = (blockIdx.x * 256 + threadIdx.x) >> 5;   // chain 0..12287
    const int j   = threadIdx.x & 31;
    const int b   = grp / 768;
    const int c1  = grp - b * 768;
    const unsigned short* basep = xt + ((size_t)grp << 10);
    const float bias_c = bias[c1];
    float* baseo = out + (size_t)b * 786432 + (size_t)(c1 >> 8) * 262144;

    // incremental emit state over the (3,544,544) view (c const per chain)
    int rem = (c1 & 255) * 1156 + j;
    int ey  = rem / 544;
    int ex  = rem - ey * 544;
    int eo  = (ey - 16) * 512 + (ex - 16);

    auto estep = [&](float v) {
        if (((unsigned)(ex - 16) < 512u) & ((unsigned)(ey - 16) < 512u))
            baseo[eo] = v;
        ex += 32;
        int wrp = (ex >= 544);
        ex -= wrp ? 544 : 0;
        ey += wrp;
        eo += wrp ? 0 : 32;
    };
    auto sel = [&](int p) -> float {            // flat 34x34 index -> value
        unsigned int h = (unsigned int)p / 34u;
        unsigned int w = (unsigned int)p - h * 34u;
        if ((h == 0u) | (h == 33u) | (w == 0u) | (w == 33u)) return bias_c;
        return bf2f(basep[(h - 1u) * 32u + (w - 1u)]);
    };

    float co = sel( 32 + j);       // row 1
    float no = sel( 64 + j);       // row 2
    float o2 = sel( 96 + j);       // row 3
    float o3 = sel(128 + j);       // row 4
    estep(bias_c);                 // flat row 0: entirely border
    float pn   = bias_c;
    float po_h = bias_c;           // head of row i-1
    float h_co = __shfl(co, 0, 32);   // head of row i
    float h_no = __shfl(no, 0, 32);   // head of row i+1
    float h_o2 = __shfl(o2, 0, 32);   // head of row i+2
    float rr   = __shfl_down(co, 1, 32);           // Rr for i=1
    if (j == 31) rr = h_no;

    for (int i = 1; i <= 30; ++i) {
        float ld = sel((i + 4) * 32 + j);           // row i+4 (max p=1119)
        float UL = __shfl_up(pn, 1, 32);   if (j == 1)  UL = po_h;
        float UR = __shfl_down(pn, 1, 32); if (j == 31) UR = h_co;
        float D1 = __shfl_up(no, 1, 32);
        float D3 = __shfl_down(no, 1, 32); if (j == 31) D3 = h_o2;
        float bv = (((UL + pn) + (UR + rr)) + ((D1 + no) + D3)) * 0.125f;
        if (j == 1) bv += h_co * 0.125f;
        float t;
        t = __shfl_up(bv, 1, 32);  bv += (j > 1) ? 0.125f * t : 0.f;
        t = __shfl_up(bv, 2, 32);  bv += (j > 2) ? 0.015625f * t : 0.f;
        t = __shfl_up(bv, 4, 32);  bv += (j > 4) ? 2.44140625e-4f * t : 0.f;
        estep((j == 0) ? co : bv);
        rr   = D3;                                  // Rr for next iter
        pn   = bv;
        po_h = h_co; h_co = h_no; h_no = h_o2;
        h_o2 = __shfl(o3, 0, 32);                   // head of new row i+2
        co = no; no = o2; o2 = o3; o3 = ld;
    }
    // regs now: co=row31, no=row32, o2=row33, o3=row34 — originals/borders
    estep(co);                                  // flats 992..1023
    estep(no);                                  // 1024..1055
    estep(o2);                                  // 1056..1087
    estep(o3);                                  // 1088..1119
    estep(sel(1120 + j));                       // 1120..1151
    if (j < 4) estep(bias_c);                   // 1152..1155: h1=33 border
}

extern "C" void kernel_launch(void* const* d_in, const int* in_sizes, int n_in,
                              void* d_out, int out_size, void* d_ws, size_t ws_size,
                              hipStream_t stream) {
    const float* x    = (const float*)d_in[0];
    const float* w    = (const float*)d_in[1];
    const float* bias = (const float*)d_in[2];
    float* out = (float*)d_out;
    unsigned short* xt = (unsigned short*)d_ws;   // 12288*1024 bf16 = 25.2 MB

    unsigned short* a_bf = (unsigned short*)d_out;          // 25.2 MB
    unsigned short* w_bf = a_bf + (size_t)16384 * 768;      // +1.18 MB

    prep_k<<<6432, 256, 0, stream>>>(x, w, a_bf, w_bf);
    conv_gemm_k<<<dim3(128, 6), 256, 0, stream>>>(a_bf, w_bf, bias, xt);
    scan_emit_k<<<1536, 256, 0, stream>>>(xt, bias, out);
}

// Round 20
// 76.174 us; speedup vs baseline: 1.0329x; 1.0329x over previous
//
#include <hip/hip_runtime.h>
#include <hip/hip_bf16.h>

// Pipeline (chain = b*768 + c1, 12288 chains):
//  d_ws  : xt [12288][1024] bf16 (interior 32x32 conv outputs ONLY) = 25.2 MB.
//          Borders of the 34x34 grid are synthesized as bias[c1] in the scan.
//  d_out : scratch for W_bf ([768][768] bf16, 1.18 MB); overwritten by scan.
//  1) prep_w_k    : w -> bf16
//  2) conv_gemm_k : A staged DIRECTLY from x (fp32) via global_load_lds with
//                   per-lane im2col source addresses (zero staging VGPRs);
//                   cvt fp32->bf16 at fragment read. B via global_load_lds
//                   from W_bf (R19 pattern). DEPTH-2 counted-vmcnt schedule:
//                   {MFMA; bar; stage(t+2); vmcnt(6); bar} — staging loads get
//                   a full iteration of latency cover, never drained to 0.
//  3) scan_emit_k : R18-verbatim wave-parallel recurrence (8 DS-ops/row),
//                   4-row prefetch, 3-step Hillis-Steele, border synthesis,
//                   incremental crop emit.

typedef __attribute__((ext_vector_type(8))) short s8v;     // 8 bf16
typedef __attribute__((ext_vector_type(4))) float f4v;     // MFMA acc
typedef __attribute__((ext_vector_type(8))) unsigned short us8;
typedef __attribute__((ext_vector_type(4))) unsigned short us4;

__device__ __forceinline__ unsigned short f2bf(float f) {
    __hip_bfloat16 h = __float2bfloat16(f);
    return *reinterpret_cast<unsigned short*>(&h);
}
__device__ __forceinline__ float bf2f(unsigned short u) {
    union { unsigned int i; float f; } c; c.i = (unsigned int)u << 16; return c.f;
}

__device__ __forceinline__ void gload_lds16(const void* g, void* l) {
    __builtin_amdgcn_global_load_lds(
        (const __attribute__((address_space(1))) unsigned int*)g,
        (__attribute__((address_space(3))) unsigned int*)l,
        16, 0, 0);
}

__global__ __launch_bounds__(256) void prep_w_k(const float* __restrict__ w,
                                                unsigned short* __restrict__ w_bf) {
    int g = blockIdx.x * 256 + threadIdx.x;    // 73728 threads, 8 floats each
    int f = g << 3;
    const float4 v0 = *(const float4*)(w + f);
    const float4 v1 = *(const float4*)(w + f + 4);
    us8 u;
    u[0] = f2bf(v0.x); u[1] = f2bf(v0.y); u[2] = f2bf(v0.z); u[3] = f2bf(v0.w);
    u[4] = f2bf(v1.x); u[5] = f2bf(v1.y); u[6] = f2bf(v1.z); u[7] = f2bf(v1.w);
    *(us8*)(w_bf + f) = u;
}

// C[m][n] = sum_k A[m][k]*W[n][k]; m=(b,ph,pw), k=(c,py,px), n=c1.
// 128x128 tile, BK=32, 4 waves (2x2 of 64x64). A in LDS as fp32 [128][32]:
// logical k-chunk (16B = 4 fp32) c of row r stored at slot (c ^ (r&7));
// staging achieves this by pre-permuting the per-lane GLOBAL source address
// (chunk_log = (l&7) ^ ((l>>3)&7)); reads apply the same XOR. 2-way max
// bank aliasing (free). B bf16 verbatim R19 (measured 0-conflict).
__global__ __launch_bounds__(256) void conv_gemm_k(const float* __restrict__ x,
                                                   const unsigned short* __restrict__ W,
                                                   const float* __restrict__ bias,
                                                   unsigned short* __restrict__ xt) {
    __shared__ __align__(16) float          Asf[2][128 * 32];   // 16 KB x2
    __shared__ __align__(16) unsigned short Bs[2][128 * 32];    //  8 KB x2
    const int tid  = threadIdx.x;
    const int lane = tid & 63, wv = tid >> 6;
    const int wr = wv >> 1, wc = wv & 1;
    const int m0 = blockIdx.x << 7, n0 = blockIdx.y << 7;
    const int bb = m0 >> 10;
    const int ph0 = (m0 >> 5) & 31;

    f4v acc[4][4] = {};

    // ---- A staging: wave wv covers rows [wv*32, wv*32+32) = (ph0+wv, pw*) ----
    // call i, lane l -> LDS 16B-unit (wv*256 + i*64 + l):
    //   row_local = i*8 + (l>>3), slot = l&7, chunk_log = (l&7)^((l>>3)&7),
    //   pw = row_local, py = py0 + (clog>>2), px0 = (clog&3)*4
    const int clog = (lane & 7) ^ ((lane >> 3) & 7);
    const float* abase = x + (size_t)bb * 786432
                           + ((ph0 + wv) * 16 + (clog >> 2)) * 512 + ((clog & 3) << 2);
    const float* asrc[4];
    #pragma unroll
    for (int i = 0; i < 4; ++i) asrc[i] = abase + ((i * 8 + (lane >> 3)) << 4);

    // ---- B staging: R19 verbatim ----
    const int l2 = lane >> 2;
    const int kx = ((lane & 3) ^ ((l2 >> 1) & 3)) << 3;
    const unsigned short* gB = W + (size_t)(n0 + (wv << 5) + l2) * 768 + kx;

    auto stage = [&](int buf, int t) {   // 6 gload_lds per wave
        const int koff = (t >> 3) * 262144 + (t & 7) * 1024;
        #pragma unroll
        for (int i = 0; i < 4; ++i)
            gload_lds16(asrc[i] + koff, Asf[buf] + (wv << 10) + (i << 8));
        const int k0 = t << 5;
        gload_lds16(gB + k0,            Bs[buf] + (wv << 10));
        gload_lds16(gB + k0 + 16 * 768, Bs[buf] + (wv << 10) + 512);
    };

    stage(0, 0);
    stage(1, 1);
    asm volatile("s_waitcnt vmcnt(6)" ::: "memory");   // buf0 landed; buf1 in flight
    asm volatile("s_barrier" ::: "memory");

    const int cq = lane >> 4, l15 = lane & 15;
    for (int t = 0; t < 24; ++t) {
        const int p = t & 1;
        s8v a[4], b[4];
        #pragma unroll
        for (int mi = 0; mi < 4; ++mi) {
            int r    = (wr << 6) + (mi << 4) + l15;
            int base = ((r >> 5) << 10) + ((r & 31) << 5);
            int s    = r & 7;
            float4 f0 = *(const float4*)(Asf[p] + base + ((((cq << 1))     ^ s) << 2));
            float4 f1 = *(const float4*)(Asf[p] + base + ((((cq << 1) | 1) ^ s) << 2));
            s8v av;
            av[0] = (short)f2bf(f0.x); av[1] = (short)f2bf(f0.y);
            av[2] = (short)f2bf(f0.z); av[3] = (short)f2bf(f0.w);
            av[4] = (short)f2bf(f1.x); av[5] = (short)f2bf(f1.y);
            av[6] = (short)f2bf(f1.z); av[7] = (short)f2bf(f1.w);
            a[mi] = av;
        }
        #pragma unroll
        for (int ni = 0; ni < 4; ++ni) {
            int rb = (wc << 6) + (ni << 4) + l15;
            b[ni] = *(const s8v*)(Bs[p] + (rb << 5) + ((cq ^ ((rb >> 1) & 3)) << 3));
        }
        #pragma unroll
        for (int mi = 0; mi < 4; ++mi)
            #pragma unroll
            for (int ni = 0; ni < 4; ++ni)
                acc[mi][ni] = __builtin_amdgcn_mfma_f32_16x16x32_bf16(a[mi], b[ni], acc[mi][ni], 0, 0, 0);
        asm volatile("s_barrier" ::: "memory");        // all waves done reading buf p
        if (t < 22) {
            stage(p, t + 2);                           // overwrite buf p (safe)
            asm volatile("s_waitcnt vmcnt(6)" ::: "memory");  // buf p^1 landed
        } else {
            asm volatile("s_waitcnt vmcnt(0)" ::: "memory");  // drain tail
        }
        asm volatile("s_barrier" ::: "memory");        // buf p^1 ready for all
    }

    // packed bf16 epilogue: lane owns 4 consecutive pw (acc regs) at one n
    #pragma unroll
    for (int mi = 0; mi < 4; ++mi) {
        int m  = m0 + (wr << 6) + (mi << 4) + (cq << 2);
        int ph = (m >> 5) & 31, pwm = m & 31;
        unsigned short* dst = xt + (((size_t)bb * 768) << 10) + (ph << 5) + pwm;
        #pragma unroll
        for (int ni = 0; ni < 4; ++ni) {
            int n = n0 + (wc << 6) + (ni << 4) + l15;
            float bv = bias[n];
            us4 o;
            o[0] = f2bf(acc[mi][ni][0] + bv);
            o[1] = f2bf(acc[mi][ni][1] + bv);
            o[2] = f2bf(acc[mi][ni][2] + bv);
            o[3] = f2bf(acc[mi][ni][3] + bv);
            *(us4*)(dst + ((size_t)n << 10)) = o;
        }
    }
}

// Wave-parallel scan + fused crop: ONE chain per 32-lane group (12288 groups).
// Shuffle-rolled: 8 DS ops per row (heads roll; Rr = previous iter's D3).
__global__ __launch_bounds__(256) void scan_emit_k(const unsigned short* __restrict__ xt,
                                                   const float* __restrict__ bias,
                                                   float* __restrict__ out) {
    const int grp = (blockIdx.x * 256 + threadIdx.x) >> 5;   // chain 0..12287
    const int j   = threadIdx.x & 31;
    const int b   = grp / 768;
    const int c1  = grp - b * 768;
    const unsigned short* basep = xt + ((size_t)grp << 10);
    const float bias_c = bias[c1];
    float* baseo = out + (size_t)b * 786432 + (size_t)(c1 >> 8) * 262144;

    // incremental emit state over the (3,544,544) view (c const per chain)
    int rem = (c1 & 255) * 1156 + j;
    int ey  = rem / 544;
    int ex  = rem - ey * 544;
    int eo  = (ey - 16) * 512 + (ex - 16);

    auto estep = [&](float v) {
        if (((unsigned)(ex - 16) < 512u) & ((unsigned)(ey - 16) < 512u))
            baseo[eo] = v;
        ex += 32;
        int wrp = (ex >= 544);
        ex -= wrp ? 544 : 0;
        ey += wrp;
        eo += wrp ? 0 : 32;
    };
    auto sel = [&](int p) -> float {            // flat 34x34 index -> value
        unsigned int h = (unsigned int)p / 34u;
        unsigned int w = (unsigned int)p - h * 34u;
        if ((h == 0u) | (h == 33u) | (w == 0u) | (w == 33u)) return bias_c;
        return bf2f(basep[(h - 1u) * 32u + (w - 1u)]);
    };

    float co = sel( 32 + j);       // row 1
    float no = sel( 64 + j);       // row 2
    float o2 = sel( 96 + j);       // row 3
    float o3 = sel(128 + j);       // row 4
    estep(bias_c);                 // flat row 0: entirely border
    float pn   = bias_c;
    float po_h = bias_c;           // head of row i-1
    float h_co = __shfl(co, 0, 32);   // head of row i
    float h_no = __shfl(no, 0, 32);   // head of row i+1
    float h_o2 = __shfl(o2, 0, 32);   // head of row i+2
    float rr   = __shfl_down(co, 1, 32);           // Rr for i=1
    if (j == 31) rr = h_no;

    for (int i = 1; i <= 30; ++i) {
        float ld = sel((i + 4) * 32 + j);           // row i+4 (max p=1119)
        float UL = __shfl_up(pn, 1, 32);   if (j == 1)  UL = po_h;
        float UR = __shfl_down(pn, 1, 32); if (j == 31) UR = h_co;
        float D1 = __shfl_up(no, 1, 32);
        float D3 = __shfl_down(no, 1, 32); if (j == 31) D3 = h_o2;
        float bv = (((UL + pn) + (UR + rr)) + ((D1 + no) + D3)) * 0.125f;
        if (j == 1) bv += h_co * 0.125f;
        float t;
        t = __shfl_up(bv, 1, 32);  bv += (j > 1) ? 0.125f * t : 0.f;
        t = __shfl_up(bv, 2, 32);  bv += (j > 2) ? 0.015625f * t : 0.f;
        t = __shfl_up(bv, 4, 32);  bv += (j > 4) ? 2.44140625e-4f * t : 0.f;
        estep((j == 0) ? co : bv);
        rr   = D3;                                  // Rr for next iter
        pn   = bv;
        po_h = h_co; h_co = h_no; h_no = h_o2;
        h_o2 = __shfl(o3, 0, 32);                   // head of new row i+2
        co = no; no = o2; o2 = o3; o3 = ld;
    }
    // regs now: co=row31, no=row32, o2=row33, o3=row34 — originals/borders
    estep(co);                                  // flats 992..1023
    estep(no);                                  // 1024..1055
    estep(o2);                                  // 1056..1087
    estep(o3);                                  // 1088..1119
    estep(sel(1120 + j));                       // 1120..1151
    if (j < 4) estep(bias_c);                   // 1152..1155: h1=33 border
}

extern "C" void kernel_launch(void* const* d_in, const int* in_sizes, int n_in,
                              void* d_out, int out_size, void* d_ws, size_t ws_size,
                              hipStream_t stream) {
    const float* x    = (const float*)d_in[0];
    const float* w    = (const float*)d_in[1];
    const float* bias = (const float*)d_in[2];
    float* out = (float*)d_out;
    unsigned short* xt = (unsigned short*)d_ws;   // 12288*1024 bf16 = 25.2 MB

    unsigned short* w_bf = (unsigned short*)d_out;   // 1.18 MB scratch in d_out

    prep_w_k<<<288, 256, 0, stream>>>(w, w_bf);
    conv_gemm_k<<<dim3(128, 6), 256, 0, stream>>>(x, w_bf, bias, xt);
    scan_emit_k<<<1536, 256, 0, stream>>>(xt, bias, out);
}